// Round 7
// baseline (604.195 us; speedup 1.0000x reference)
//
#include <hip/hip_runtime.h>

#define BATCH 128
#define SEQ   256

// ws layout (floats): [0] t_star, [1] chunked-ok flag
#define WS_K  16                      // K table [SEQ][64][64], row e = gain row for out elem e
#define WS_A  (16 + SEQ * 4096)       // A* = (I-K*H)F row-major
#define WS_BP (WS_A + 4096)           // Bp = (I-K*H)B row-major
#define WS_KS (WS_BP + 4096)          // K* row-major (same row convention as WS_K)

typedef unsigned short u16;
typedef float  f32x4v __attribute__((ext_vector_type(4)));
typedef __bf16 bf16x8 __attribute__((ext_vector_type(8)));
typedef unsigned short u16x8 __attribute__((ext_vector_type(8)));

struct Acc { f32x4v t[2][2]; };

__device__ __forceinline__ u16 bf16hi(float x) {
  unsigned u = __float_as_uint(x);
  return (u16)((u + 0x7fffu + ((u >> 16) & 1u)) >> 16);
}
__device__ __forceinline__ float bf16f(u16 h) {
  return __uint_as_float(((unsigned)h) << 16);
}

__device__ __forceinline__ int swadr(int a, int c) {
  return a * 64 + ((c ^ (a & 7)) << 3);
}

__device__ __forceinline__ bf16x8 frag(const u16* M, int strip, int kb, int q, int ln) {
  return *(const bf16x8*)(M + swadr(strip * 16 + ln, kb * 4 + q));
}

// acc += A @ B over K=64 with 3-term split-bf16. A: R-form, B: T-form (or symmetric R)
__device__ __forceinline__ void mm(const u16* As, const u16* Bs, Acc& acc,
                                   int R, int Cb, int q, int ln) {
#pragma unroll
  for (int kb = 0; kb < 2; ++kb) {
    bf16x8 ah[2], al[2], bh[2], bl[2];
#pragma unroll
    for (int i = 0; i < 2; ++i) {
      ah[i] = frag(As,        2 * R  + i, kb, q, ln);
      al[i] = frag(As + 4096, 2 * R  + i, kb, q, ln);
      bh[i] = frag(Bs,        2 * Cb + i, kb, q, ln);
      bl[i] = frag(Bs + 4096, 2 * Cb + i, kb, q, ln);
    }
#pragma unroll
    for (int i = 0; i < 2; ++i)
#pragma unroll
      for (int j = 0; j < 2; ++j) {
        acc.t[i][j] = __builtin_amdgcn_mfma_f32_16x16x32_bf16(ah[i], bh[j], acc.t[i][j], 0, 0, 0);
        acc.t[i][j] = __builtin_amdgcn_mfma_f32_16x16x32_bf16(ah[i], bl[j], acc.t[i][j], 0, 0, 0);
        acc.t[i][j] = __builtin_amdgcn_mfma_f32_16x16x32_bf16(al[i], bh[j], acc.t[i][j], 0, 0, 0);
      }
  }
}

__device__ __forceinline__ Acc accZero() {
  Acc a;
#pragma unroll
  for (int i = 0; i < 2; ++i)
#pragma unroll
    for (int j = 0; j < 2; ++j) {
      f32x4v z; z.x = 0.f; z.y = 0.f; z.z = 0.f; z.w = 0.f;
      a.t[i][j] = z;
    }
  return a;
}

__device__ __forceinline__ void storeC(float* dst, const Acc& a, int R, int Cb, int q, int ln) {
#pragma unroll
  for (int i = 0; i < 2; ++i)
#pragma unroll
    for (int j = 0; j < 2; ++j)
#pragma unroll
      for (int k = 0; k < 4; ++k)
        dst[(32 * R + 16 * i + 4 * q + k) * 64 + 32 * Cb + 16 * j + ln] = a.t[i][j][k];
}

__device__ __forceinline__ void emit16(const float* v, int row, int cb, u16* Rs, u16* Ts) {
  u16 h[16], lo[16];
#pragma unroll
  for (int e = 0; e < 16; ++e) {
    h[e] = bf16hi(v[e]);
    lo[e] = bf16hi(v[e] - bf16f(h[e]));
  }
  if (Rs) {
#pragma unroll
    for (int c = 0; c < 2; ++c) {
      u16x8 vh, vl;
#pragma unroll
      for (int e = 0; e < 8; ++e) { vh[e] = h[8 * c + e]; vl[e] = lo[8 * c + e]; }
      const int ad = swadr(row, (cb >> 3) + c);
      *(u16x8*)(Rs + ad) = vh;
      *(u16x8*)(Rs + 4096 + ad) = vl;
    }
  }
  if (Ts) {
    const int rc = row >> 3, rr = row & 7;
#pragma unroll
    for (int e = 0; e < 16; ++e) {
      const int a = cb + e;
      const int ad = a * 64 + ((rc ^ (a & 7)) << 3) + rr;
      Ts[ad] = h[e];
      Ts[4096 + ad] = lo[e];
    }
  }
}

// mode 0: v=src; 1: v=src*scale; 2: v=(diag?dval:0)-src
__device__ __forceinline__ void splitsrc(const float* src, u16* Rs, u16* Ts,
                                         int mode, float scale, float dval, int tid) {
  const int row = tid >> 2, cb = (tid & 3) << 4;
  float v[16];
#pragma unroll
  for (int m = 0; m < 4; ++m) {
    f32x4v x = *(const f32x4v*)(src + row * 64 + cb + 4 * m);
    v[4 * m] = x.x; v[4 * m + 1] = x.y; v[4 * m + 2] = x.z; v[4 * m + 3] = x.w;
  }
  if (mode == 1) {
#pragma unroll
    for (int e = 0; e < 16; ++e) v[e] *= scale;
  } else if (mode == 2) {
#pragma unroll
    for (int e = 0; e < 16; ++e) v[e] = (((cb + e) == row) ? dval : 0.f) - v[e];
  }
  emit16(v, row, cb, Rs, Ts);
}

__device__ __forceinline__ float redmax(float v, float* red, int tid) {
#pragma unroll
  for (int off = 32; off > 0; off >>= 1) v = fmaxf(v, __shfl_xor(v, off));
  if ((tid & 63) == 0) red[300 + (tid >> 6)] = v;
  __syncthreads();
  float m = fmaxf(fmaxf(red[300], red[301]), fmaxf(red[302], red[303]));
  __syncthreads();
  return m;
}

__device__ __forceinline__ float dot4(float4 a, float4 b, float acc) {
  return fmaf(a.x, b.x, fmaf(a.y, b.y, fmaf(a.z, b.z, fmaf(a.w, b.w, acc))));
}

// ---------------- Kernel 1: Riccati. Diagonal fast path + general MFMA path ----------
__global__ void __launch_bounds__(256, 1)
k1_riccati(const float* __restrict__ Fg, const float* __restrict__ Bg,
           const float* __restrict__ Hg, const float* __restrict__ LQg,
           const float* __restrict__ LRg, float* __restrict__ ws,
           float* __restrict__ covs) {
  __shared__ __align__(16) u16 smb[7 * 8192];
  __shared__ __align__(16) float Mf32[4096];
  __shared__ __align__(16) float Ppf32[4096];
  __shared__ __align__(16) float red[308];

  const int tid = threadIdx.x;
  const int l = tid & 63, w = tid >> 6, q = l >> 4, ln = l & 15;
  const int R = w >> 1, Cb = w & 1;

  // ---- diagonality detection ----
  {
    const int row = tid >> 2, cb = (tid & 3) << 4;
    float od = 0.f;
    const float* mats[5] = {Fg, Bg, Hg, LQg, LRg};
#pragma unroll
    for (int mi = 0; mi < 5; ++mi) {
      const float* M = mats[mi];
#pragma unroll
      for (int m = 0; m < 4; ++m) {
        f32x4v x = *(const f32x4v*)(M + row * 64 + cb + 4 * m);
        const int j0c = cb + 4 * m;
        if (j0c + 0 != row) od = fmaxf(od, fabsf(x.x));
        if (j0c + 1 != row) od = fmaxf(od, fabsf(x.y));
        if (j0c + 2 != row) od = fmaxf(od, fabsf(x.z));
        if (j0c + 3 != row) od = fmaxf(od, fabsf(x.w));
      }
    }
    const float odall = redmax(od, red, tid);
    if (odall == 0.f) {
      if (tid < 64) {
        const int e = tid;
        const float f = Fg[e * 65], b = Bg[e * 65], h = Hg[e * 65];
        const float lq = LQg[e * 65], lr = LRg[e * 65];
        const float qv = lq * lq, rv = lr * lr;
        float p = 1.f, kprev = 0.f, kcur = 0.f, om = 1.f;
        int tstar = SEQ - 1;
        for (int t = 0; t < SEQ; ++t) {
          const float pp = f * p * f + qv;
          const float s = h * pp * h + rv;
          const float k = pp * h / s;
          const float kh = k * h;
          const float omv = 1.f - kh;
          const float pn = omv * omv * pp + k * k * rv;
          float* Kt = ws + WS_K + (size_t)t * 4096 + e * 64;
          float* Ct = covs + (size_t)t * 4096 + e * 64;
          f32x4v z; z.x = 0.f; z.y = 0.f; z.z = 0.f; z.w = 0.f;
#pragma unroll
          for (int m = 0; m < 16; ++m) {
            *(f32x4v*)(Kt + 4 * m) = z;
            *(f32x4v*)(Ct + 4 * m) = z;
          }
          Kt[e] = k;
          Ct[e] = pn;
          float dk = (t == 0) ? 1e9f : fabsf(k - kprev);
#pragma unroll
          for (int off = 32; off > 0; off >>= 1) dk = fmaxf(dk, __shfl_xor(dk, off));
          p = pn; kprev = k; kcur = k; om = omv;
          if (dk < 1e-3f) { tstar = t; break; }
        }
        {
          const float astar = om * f, bpv = om * b;
          float* Ar = ws + WS_A + e * 64;
          float* Bp = ws + WS_BP + e * 64;
          float* Ks = ws + WS_KS + e * 64;
          f32x4v z; z.x = 0.f; z.y = 0.f; z.z = 0.f; z.w = 0.f;
#pragma unroll
          for (int m = 0; m < 16; ++m) {
            *(f32x4v*)(Ar + 4 * m) = z;
            *(f32x4v*)(Bp + 4 * m) = z;
            *(f32x4v*)(Ks + 4 * m) = z;
          }
          Ar[e] = astar; Bp[e] = bpv; Ks[e] = kcur;
          const float a2 = astar * astar, a4 = a2 * a2, a8 = a4 * a4;
          float a16 = fabsf(a8 * a8);
#pragma unroll
          for (int off = 32; off > 0; off >>= 1) a16 = fmaxf(a16, __shfl_xor(a16, off));
          if (e == 0) {
            ((int*)ws)[0] = tstar;
            ((int*)ws)[1] = (tstar <= 16 && a16 < 1e-5f) ? 1 : 0;
          }
        }
      }
      return;
    }
  }

  // ======== general path: split-bf16 MFMA Riccati ========
  u16* SF = smb;
  u16* SH = smb + 8192;
  u16* SX = smb + 2 * 8192;
  u16* S1 = smb + 3 * 8192;
  u16* S2 = smb + 4 * 8192;
  u16* S3 = smb + 5 * 8192;
  u16* S4 = smb + 6 * 8192;

  splitsrc(Fg, SF, nullptr, 0, 0, 0, tid);
  splitsrc(Hg, SH, nullptr, 0, 0, 0, tid);
  splitsrc(LQg, S1, nullptr, 0, 0, 0, tid);
  __syncthreads();
  Acc qacc = accZero(); mm(S1, S1, qacc, R, Cb, q, ln);
  __syncthreads();
  splitsrc(LRg, S1, nullptr, 0, 0, 0, tid);
  __syncthreads();
  Acc racc = accZero(); mm(S1, S1, racc, R, Cb, q, ln);
  __syncthreads();
  {
    const int row = tid >> 2, cb = (tid & 3) << 4;
    float v[16];
#pragma unroll
    for (int e = 0; e < 16; ++e) v[e] = ((cb + e) == row) ? 1.f : 0.f;
    emit16(v, row, cb, S4, nullptr);   // P0 = I
  }
  __syncthreads();

  int tstar = SEQ - 1;
  for (int t = 0; t < SEQ; ++t) {
    const u16* Wsrc = SF;
    if (t > 0) {
      Acc a = accZero(); mm(SF, S4, a, R, Cb, q, ln);
      storeC(Mf32, a, R, Cb, q, ln);
      __syncthreads();
      splitsrc(Mf32, S1, nullptr, 0, 0, 0, tid);
      __syncthreads();
      Wsrc = S1;
    }
    {
      Acc a = qacc; mm(Wsrc, SF, a, R, Cb, q, ln);
      storeC(Ppf32, a, R, Cb, q, ln);
      __syncthreads();
      splitsrc(Ppf32, S2, nullptr, 0, 0, 0, tid);
      __syncthreads();
    }
    {
      Acc a = accZero(); mm(SH, S2, a, R, Cb, q, ln);
      storeC(Mf32, a, R, Cb, q, ln);
      __syncthreads();
      splitsrc(Mf32, S3, S4, 0, 0, 0, tid);
      __syncthreads();
    }
    {
      Acc a = racc; mm(S3, SH, a, R, Cb, q, ln);
      storeC(Mf32, a, R, Cb, q, ln);
      __syncthreads();
      if (t == 0) {
        const int col = tid & 63, grp = tid >> 6;
        float s = 0.f;
        for (int r2 = grp * 16; r2 < grp * 16 + 16; ++r2) s += fabsf(Mf32[r2 * 64 + col]);
        red[tid] = s;
        __syncthreads();
        if (tid < 64) {
          float cs = red[tid] + red[64 + tid] + red[128 + tid] + red[192 + tid];
#pragma unroll
          for (int off = 32; off > 0; off >>= 1) cs = fmaxf(cs, __shfl_xor(cs, off));
          if (tid == 0) red[256] = 1.f / (cs * cs);
        }
        __syncthreads();
        const float sc = red[256];
        splitsrc(Mf32, SX, nullptr, 1, sc, 0, tid);
        __syncthreads();
      }
      splitsrc(Mf32, S2, nullptr, 0, 0, 0, tid);
      __syncthreads();
    }
    const int cap = (t == 0) ? 40 : 4;
    for (int it = 0; it < cap; ++it) {
      Acc e_ = accZero(); mm(S2, SX, e_, R, Cb, q, ln);
      float r = 0.f;
#pragma unroll
      for (int i = 0; i < 2; ++i)
#pragma unroll
        for (int j = 0; j < 2; ++j)
#pragma unroll
          for (int k = 0; k < 4; ++k) {
            const int gr = 32 * R + 16 * i + 4 * q + k;
            const int gc = 32 * Cb + 16 * j + ln;
            r = fmaxf(r, fabsf(e_.t[i][j][k] - ((gr == gc) ? 1.f : 0.f)));
          }
      const float rall = redmax(r, red, tid);
      if (rall < 5e-4f) break;
      storeC(Mf32, e_, R, Cb, q, ln);
      __syncthreads();
      splitsrc(Mf32, nullptr, S1, 2, 0, 2.0f, tid);
      __syncthreads();
      Acc x2 = accZero(); mm(SX, S1, x2, R, Cb, q, ln);
      storeC(Mf32, x2, R, Cb, q, ln);
      __syncthreads();
      splitsrc(Mf32, SX, nullptr, 0, 0, 0, tid);
      __syncthreads();
      if (rall * rall < 1e-4f) break;
    }
    __syncthreads();
    float dk;
    {
      Acc a = accZero(); mm(SX, S4, a, R, Cb, q, ln);
      storeC(Mf32, a, R, Cb, q, ln);
      __syncthreads();
      const int row = tid >> 2, cb = (tid & 3) << 4;
      float v[16]; float dmax = (t == 0) ? 1e9f : 0.f;
      float* wrow = ws + WS_K + (size_t)t * 4096 + row * 64 + cb;
#pragma unroll
      for (int m = 0; m < 4; ++m) {
        f32x4v x = *(const f32x4v*)(Mf32 + row * 64 + cb + 4 * m);
        v[4 * m] = x.x; v[4 * m + 1] = x.y; v[4 * m + 2] = x.z; v[4 * m + 3] = x.w;
        *(f32x4v*)(wrow + 4 * m) = x;
      }
      if (t > 0) {
        const float* prow = wrow - 4096;
#pragma unroll
        for (int m = 0; m < 4; ++m) {
          f32x4v p = *(const f32x4v*)(prow + 4 * m);
          dmax = fmaxf(dmax, fmaxf(fmaxf(fabsf(v[4 * m] - p.x), fabsf(v[4 * m + 1] - p.y)),
                                   fmaxf(fabsf(v[4 * m + 2] - p.z), fabsf(v[4 * m + 3] - p.w))));
        }
      }
      emit16(v, row, cb, nullptr, S1);
      dk = redmax(dmax, red, tid);
    }
    {
      Acc a = accZero(); mm(S1, S4, a, R, Cb, q, ln);
      storeC(Mf32, a, R, Cb, q, ln);
      __syncthreads();
      const int row = tid >> 2, cb = (tid & 3) << 4;
      float pv[16];
#pragma unroll
      for (int m = 0; m < 4; ++m) {
        f32x4v mij = *(const f32x4v*)(Mf32 + row * 64 + cb + 4 * m);
        f32x4v pp  = *(const f32x4v*)(Ppf32 + row * 64 + cb + 4 * m);
        pv[4 * m]     = pp.x - 0.5f * (mij.x + Mf32[(cb + 4 * m + 0) * 64 + row]);
        pv[4 * m + 1] = pp.y - 0.5f * (mij.y + Mf32[(cb + 4 * m + 1) * 64 + row]);
        pv[4 * m + 2] = pp.z - 0.5f * (mij.z + Mf32[(cb + 4 * m + 2) * 64 + row]);
        pv[4 * m + 3] = pp.w - 0.5f * (mij.w + Mf32[(cb + 4 * m + 3) * 64 + row]);
      }
      float* crow = covs + (size_t)t * 4096 + row * 64 + cb;
#pragma unroll
      for (int m = 0; m < 4; ++m) {
        f32x4v o; o.x = pv[4 * m]; o.y = pv[4 * m + 1]; o.z = pv[4 * m + 2]; o.w = pv[4 * m + 3];
        *(f32x4v*)(crow + 4 * m) = o;
      }
      emit16(pv, row, cb, S4, nullptr);
      __syncthreads();
    }
    if (dk < 1e-3f) { tstar = t; break; }
  }

  {
    Acc a = accZero(); mm(S1, SH, a, R, Cb, q, ln);
    storeC(Mf32, a, R, Cb, q, ln);
    __syncthreads();
    splitsrc(Mf32, S2, nullptr, 2, 0, 1.0f, tid);
    __syncthreads();
  }
  splitsrc(Fg, nullptr, S3, 0, 0, 0, tid);
  __syncthreads();
  {
    Acc a = accZero(); mm(S2, S3, a, R, Cb, q, ln);
    storeC(Mf32, a, R, Cb, q, ln);
#pragma unroll
    for (int i = 0; i < 2; ++i)
#pragma unroll
      for (int j = 0; j < 2; ++j)
#pragma unroll
        for (int k = 0; k < 4; ++k)
          ws[WS_A + (size_t)((32 * R + 16 * i + 4 * q + k) * 64 + 32 * Cb + 16 * j + ln)] = a.t[i][j][k];
    __syncthreads();
    splitsrc(Mf32, S1, S4, 0, 0, 0, tid);
    __syncthreads();
  }
  splitsrc(Bg, nullptr, S3, 0, 0, 0, tid);
  __syncthreads();
  {
    Acc a = accZero(); mm(S2, S3, a, R, Cb, q, ln);
#pragma unroll
    for (int i = 0; i < 2; ++i)
#pragma unroll
      for (int j = 0; j < 2; ++j)
#pragma unroll
        for (int k = 0; k < 4; ++k)
          ws[WS_BP + (size_t)((32 * R + 16 * i + 4 * q + k) * 64 + 32 * Cb + 16 * j + ln)] = a.t[i][j][k];
  }
  {
    const int row = tid >> 2, cb = (tid & 3) << 4;
    const float* srcr = ws + WS_K + (size_t)tstar * 4096 + row * 64 + cb;
    float* dstr = ws + WS_KS + row * 64 + cb;
#pragma unroll
    for (int m = 0; m < 4; ++m) *(f32x4v*)(dstr + 4 * m) = *(const f32x4v*)(srcr + 4 * m);
  }
  __syncthreads();
  {
    Acc a = accZero(); mm(S1, S4, a, R, Cb, q, ln);
    storeC(Mf32, a, R, Cb, q, ln); __syncthreads();
    splitsrc(Mf32, S2, S3, 0, 0, 0, tid); __syncthreads();
  }
  {
    Acc a = accZero(); mm(S2, S3, a, R, Cb, q, ln);
    storeC(Mf32, a, R, Cb, q, ln); __syncthreads();
    splitsrc(Mf32, S1, S4, 0, 0, 0, tid); __syncthreads();
  }
  {
    Acc a = accZero(); mm(S1, S4, a, R, Cb, q, ln);
    storeC(Mf32, a, R, Cb, q, ln); __syncthreads();
    splitsrc(Mf32, S2, S3, 0, 0, 0, tid); __syncthreads();
  }
  {
    Acc a = accZero(); mm(S2, S3, a, R, Cb, q, ln);
    float am = 0.f;
#pragma unroll
    for (int i = 0; i < 2; ++i)
#pragma unroll
      for (int j = 0; j < 2; ++j)
#pragma unroll
        for (int k = 0; k < 4; ++k) am = fmaxf(am, fabsf(a.t[i][j][k]));
    const float amax = redmax(am, red, tid);
    if (tid == 0) {
      ((int*)ws)[0] = tstar;
      ((int*)ws)[1] = (tstar <= 16 && amax < 1e-5f) ? 1 : 0;
    }
  }
}

// ------- Kernel 2: batch-contiguous broadcast (fill-like writes) + x-recursion -------
#define NB2 512    // 128 batches x 4 s-quarters -> each WG writes 1 MB CONTIGUOUS
#define NX2 1024   // 8 chunks x 128 batches

__global__ void __launch_bounds__(256, 4)
k2_fused(const float* __restrict__ x0, const float* __restrict__ U,
         const float* __restrict__ Y, const float* __restrict__ Fg,
         const float* __restrict__ Bg, const float* __restrict__ Hg,
         const float* __restrict__ ws, float* __restrict__ preds,
         float* __restrict__ covs) {
  const int tid = threadIdx.x;
  const int wg = blockIdx.x;
  const int tstar = ((const int*)ws)[0];
  const int flag  = ((const int*)ws)[1];

  if (wg < NB2) {
    // covs broadcast, batch-contiguous: WG (b, quarter) writes s-rows s0..s0+63 of
    // batch b — 64 consecutive 16 KB rows = 1 MB linear stream (fill-like pattern).
    const int b = wg >> 2, qt = wg & 3;
    const int s0 = qt << 6;
    const float4* srcInf = (const float4*)(covs + (size_t)tstar * 4096);
    float4 r0 = srcInf[tid], r1 = srcInf[256 + tid];
    float4 r2 = srcInf[512 + tid], r3 = srcInf[768 + tid];
    for (int s = s0; s < s0 + 64; ++s) {
      float4* dst = (float4*)(covs + ((size_t)b * SEQ + s) * 4096);
      if (s <= tstar) {
        if (b == 0) continue;  // k1 wrote batch-0 rows 0..tstar
        const float4* src = (const float4*)(covs + (size_t)s * 4096);
        dst[tid] = src[tid]; dst[256 + tid] = src[256 + tid];
        dst[512 + tid] = src[512 + tid]; dst[768 + tid] = src[768 + tid];
      } else {
        dst[tid] = r0; dst[256 + tid] = r1; dst[512 + tid] = r2; dst[768 + tid] = r3;
      }
    }
  } else {
    const int xw = wg - NB2;
    const int c = xw >> 7, b = xw & 127;
    const int e = tid >> 2, q = tid & 3;
    const int co = q << 4;  // column offset of this thread's quarter-row
    __shared__ __align__(16) float xa[64], xb[64], inn[64], us[2][64], ys[2][64];

    if (c == 0) {
      // exact path: time-varying K for t <= t*; covers all t if !flag
      const int t1 = flag ? 32 : SEQ;
      float4 Fr[4], Br[4], Hr[4], Kr[4];
      {
        const float4* fp = (const float4*)(Fg + e * 64 + co);
        const float4* bp = (const float4*)(Bg + e * 64 + co);
        const float4* hp = (const float4*)(Hg + e * 64 + co);
#pragma unroll
        for (int m = 0; m < 4; ++m) { Fr[m] = fp[m]; Br[m] = bp[m]; Hr[m] = hp[m]; }
      }
      if (tid < 64) xa[tid] = x0[b * 64 + tid];
      int staged = -1;
      for (int t = 0; t < t1; ++t) {
        const int se = (t < tstar) ? t : tstar;
        if (se != staged) {
          const float4* kp = (const float4*)(ws + WS_K + (size_t)se * 4096 + e * 64 + co);
#pragma unroll
          for (int m = 0; m < 4; ++m) Kr[m] = kp[m];
          staged = se;
        }
        if (tid < 64) us[0][tid] = U[((size_t)b * SEQ + t) * 64 + tid];
        else if (tid < 128) ys[0][tid - 64] = Y[((size_t)b * SEQ + t) * 64 + (tid - 64)];
        __syncthreads();
        const float4* xv4 = (const float4*)xa;
        const float4* us4 = (const float4*)us[0];
        float v = 0.f;
#pragma unroll
        for (int m = 0; m < 4; ++m) {
          v = dot4(Fr[m], xv4[q * 4 + m], v);
          v = dot4(Br[m], us4[q * 4 + m], v);
        }
        v += __shfl_xor(v, 1); v += __shfl_xor(v, 2);
        if (q == 0) xb[e] = v;
        __syncthreads();
        const float4* xp4 = (const float4*)xb;
        float wv = 0.f;
#pragma unroll
        for (int m = 0; m < 4; ++m) wv = dot4(Hr[m], xp4[q * 4 + m], wv);
        wv += __shfl_xor(wv, 1); wv += __shfl_xor(wv, 2);
        if (q == 0) inn[e] = ys[0][e] - wv;
        __syncthreads();
        const float4* in4 = (const float4*)inn;
        float z = 0.f;
#pragma unroll
        for (int m = 0; m < 4; ++m) z = dot4(Kr[m], in4[q * 4 + m], z);
        z += __shfl_xor(z, 1); z += __shfl_xor(z, 2);
        if (q == 0) xa[e] = xb[e] + z;
        __syncthreads();
        if (tid < 64) preds[((size_t)b * SEQ + t) * 64 + tid] = xa[tid];
      }
    } else {
      if (!flag) return;  // fallback: chunk 0 handles everything
      // steady chunk, ONE barrier/step: x_t = A* x + Bp u_t + K* y_t; burn-in 16
      const int tb = 32 * c - 16, out0 = 32 * c, t1 = 32 * c + 32;
      float4 Ar[4], Pr[4], Sr[4];
      {
        const float4* ap = (const float4*)(ws + WS_A + e * 64 + co);
        const float4* pp = (const float4*)(ws + WS_BP + e * 64 + co);
        const float4* sp = (const float4*)(ws + WS_KS + e * 64 + co);
#pragma unroll
        for (int m = 0; m < 4; ++m) { Ar[m] = ap[m]; Pr[m] = pp[m]; Sr[m] = sp[m]; }
      }
      float* xcur = xa;
      float* xnxt = xb;
      if (tid < 64) xcur[tid] = 0.f;
      float g = 0.f;
      if (tid < 64) g = U[((size_t)b * SEQ + tb) * 64 + tid];
      else if (tid < 128) g = Y[((size_t)b * SEQ + tb) * 64 + (tid - 64)];
      if (tid < 64) us[0][tid] = g;
      else if (tid < 128) ys[0][tid - 64] = g;
      if (tb + 1 < t1) {
        if (tid < 64) g = U[((size_t)b * SEQ + tb + 1) * 64 + tid];
        else if (tid < 128) g = Y[((size_t)b * SEQ + tb + 1) * 64 + (tid - 64)];
      }
      __syncthreads();
      int pb = 0;
      for (int t = tb; t < t1; ++t) {
        const float4* xv4 = (const float4*)xcur;
        const float4* us4 = (const float4*)us[pb];
        const float4* ys4 = (const float4*)ys[pb];
        float v = 0.f;
#pragma unroll
        for (int m = 0; m < 4; ++m) {
          v = dot4(Ar[m], xv4[q * 4 + m], v);
          v = dot4(Pr[m], us4[q * 4 + m], v);
          v = dot4(Sr[m], ys4[q * 4 + m], v);
        }
        v += __shfl_xor(v, 1); v += __shfl_xor(v, 2);
        if (q == 0) xnxt[e] = v;
        if (t >= out0 && q == 0) preds[((size_t)b * SEQ + t) * 64 + e] = v;
        if (t + 1 < t1) {  // stage next inputs into the other buffer; prefetch t+2
          if (tid < 64) us[pb ^ 1][tid] = g;
          else if (tid < 128) ys[pb ^ 1][tid - 64] = g;
          if (t + 2 < t1) {
            if (tid < 64) g = U[((size_t)b * SEQ + t + 2) * 64 + tid];
            else if (tid < 128) g = Y[((size_t)b * SEQ + t + 2) * 64 + (tid - 64)];
          }
        }
        __syncthreads();  // xnxt visible; us/ys[pb^1] staged; us/ys[pb] free
        { float* tp = xcur; xcur = xnxt; xnxt = tp; }
        pb ^= 1;
      }
    }
  }
}

extern "C" void kernel_launch(void* const* d_in, const int* in_sizes, int n_in,
                              void* d_out, int out_size, void* d_ws, size_t ws_size,
                              hipStream_t stream) {
  (void)in_sizes; (void)n_in; (void)out_size; (void)ws_size;
  const float* x0 = (const float*)d_in[0];
  const float* U  = (const float*)d_in[1];
  const float* Y  = (const float*)d_in[2];
  const float* F  = (const float*)d_in[3];
  const float* B  = (const float*)d_in[4];
  const float* H  = (const float*)d_in[5];
  const float* LQ = (const float*)d_in[6];
  const float* LR = (const float*)d_in[7];
  float* preds = (float*)d_out;
  float* covs  = preds + (size_t)BATCH * SEQ * 64;
  float* ws    = (float*)d_ws;  // needs ~4.25 MB

  hipLaunchKernelGGL(k1_riccati, dim3(1), dim3(256), 0, stream,
                     F, B, H, LQ, LR, ws, covs);
  hipLaunchKernelGGL(k2_fused, dim3(NB2 + NX2), dim3(256), 0, stream,
                     x0, U, Y, F, B, H, ws, preds, covs);
}

// Round 8
// 595.038 us; speedup vs baseline: 1.0154x; 1.0154x over previous
//
#include <hip/hip_runtime.h>

#define BATCH 128
#define SEQ   256

// ws layout (floats): [0] t_star, [1] chunked-ok flag
#define WS_K  16                      // K table [SEQ][64][64], row e = gain row for out elem e
#define WS_A  (16 + SEQ * 4096)       // A* = (I-K*H)F row-major
#define WS_BP (WS_A + 4096)           // Bp = (I-K*H)B row-major
#define WS_KS (WS_BP + 4096)          // K* row-major (same row convention as WS_K)

typedef unsigned short u16;
typedef float  f32x4v __attribute__((ext_vector_type(4)));
typedef __bf16 bf16x8 __attribute__((ext_vector_type(8)));
typedef unsigned short u16x8 __attribute__((ext_vector_type(8)));

struct Acc { f32x4v t[2][2]; };

__device__ __forceinline__ u16 bf16hi(float x) {
  unsigned u = __float_as_uint(x);
  return (u16)((u + 0x7fffu + ((u >> 16) & 1u)) >> 16);
}
__device__ __forceinline__ float bf16f(u16 h) {
  return __uint_as_float(((unsigned)h) << 16);
}

__device__ __forceinline__ int swadr(int a, int c) {
  return a * 64 + ((c ^ (a & 7)) << 3);
}

__device__ __forceinline__ bf16x8 frag(const u16* M, int strip, int kb, int q, int ln) {
  return *(const bf16x8*)(M + swadr(strip * 16 + ln, kb * 4 + q));
}

// acc += A @ B over K=64 with 3-term split-bf16. A: R-form, B: T-form (or symmetric R)
__device__ __forceinline__ void mm(const u16* As, const u16* Bs, Acc& acc,
                                   int R, int Cb, int q, int ln) {
#pragma unroll
  for (int kb = 0; kb < 2; ++kb) {
    bf16x8 ah[2], al[2], bh[2], bl[2];
#pragma unroll
    for (int i = 0; i < 2; ++i) {
      ah[i] = frag(As,        2 * R  + i, kb, q, ln);
      al[i] = frag(As + 4096, 2 * R  + i, kb, q, ln);
      bh[i] = frag(Bs,        2 * Cb + i, kb, q, ln);
      bl[i] = frag(Bs + 4096, 2 * Cb + i, kb, q, ln);
    }
#pragma unroll
    for (int i = 0; i < 2; ++i)
#pragma unroll
      for (int j = 0; j < 2; ++j) {
        acc.t[i][j] = __builtin_amdgcn_mfma_f32_16x16x32_bf16(ah[i], bh[j], acc.t[i][j], 0, 0, 0);
        acc.t[i][j] = __builtin_amdgcn_mfma_f32_16x16x32_bf16(ah[i], bl[j], acc.t[i][j], 0, 0, 0);
        acc.t[i][j] = __builtin_amdgcn_mfma_f32_16x16x32_bf16(al[i], bh[j], acc.t[i][j], 0, 0, 0);
      }
  }
}

__device__ __forceinline__ Acc accZero() {
  Acc a;
#pragma unroll
  for (int i = 0; i < 2; ++i)
#pragma unroll
    for (int j = 0; j < 2; ++j) {
      f32x4v z; z.x = 0.f; z.y = 0.f; z.z = 0.f; z.w = 0.f;
      a.t[i][j] = z;
    }
  return a;
}

__device__ __forceinline__ void storeC(float* dst, const Acc& a, int R, int Cb, int q, int ln) {
#pragma unroll
  for (int i = 0; i < 2; ++i)
#pragma unroll
    for (int j = 0; j < 2; ++j)
#pragma unroll
      for (int k = 0; k < 4; ++k)
        dst[(32 * R + 16 * i + 4 * q + k) * 64 + 32 * Cb + 16 * j + ln] = a.t[i][j][k];
}

__device__ __forceinline__ void emit16(const float* v, int row, int cb, u16* Rs, u16* Ts) {
  u16 h[16], lo[16];
#pragma unroll
  for (int e = 0; e < 16; ++e) {
    h[e] = bf16hi(v[e]);
    lo[e] = bf16hi(v[e] - bf16f(h[e]));
  }
  if (Rs) {
#pragma unroll
    for (int c = 0; c < 2; ++c) {
      u16x8 vh, vl;
#pragma unroll
      for (int e = 0; e < 8; ++e) { vh[e] = h[8 * c + e]; vl[e] = lo[8 * c + e]; }
      const int ad = swadr(row, (cb >> 3) + c);
      *(u16x8*)(Rs + ad) = vh;
      *(u16x8*)(Rs + 4096 + ad) = vl;
    }
  }
  if (Ts) {
    const int rc = row >> 3, rr = row & 7;
#pragma unroll
    for (int e = 0; e < 16; ++e) {
      const int a = cb + e;
      const int ad = a * 64 + ((rc ^ (a & 7)) << 3) + rr;
      Ts[ad] = h[e];
      Ts[4096 + ad] = lo[e];
    }
  }
}

// mode 0: v=src; 1: v=src*scale; 2: v=(diag?dval:0)-src
__device__ __forceinline__ void splitsrc(const float* src, u16* Rs, u16* Ts,
                                         int mode, float scale, float dval, int tid) {
  const int row = tid >> 2, cb = (tid & 3) << 4;
  float v[16];
#pragma unroll
  for (int m = 0; m < 4; ++m) {
    f32x4v x = *(const f32x4v*)(src + row * 64 + cb + 4 * m);
    v[4 * m] = x.x; v[4 * m + 1] = x.y; v[4 * m + 2] = x.z; v[4 * m + 3] = x.w;
  }
  if (mode == 1) {
#pragma unroll
    for (int e = 0; e < 16; ++e) v[e] *= scale;
  } else if (mode == 2) {
#pragma unroll
    for (int e = 0; e < 16; ++e) v[e] = (((cb + e) == row) ? dval : 0.f) - v[e];
  }
  emit16(v, row, cb, Rs, Ts);
}

__device__ __forceinline__ float redmax(float v, float* red, int tid) {
#pragma unroll
  for (int off = 32; off > 0; off >>= 1) v = fmaxf(v, __shfl_xor(v, off));
  if ((tid & 63) == 0) red[300 + (tid >> 6)] = v;
  __syncthreads();
  float m = fmaxf(fmaxf(red[300], red[301]), fmaxf(red[302], red[303]));
  __syncthreads();
  return m;
}

__device__ __forceinline__ float dot4(float4 a, float4 b, float acc) {
  return fmaf(a.x, b.x, fmaf(a.y, b.y, fmaf(a.z, b.z, fmaf(a.w, b.w, acc))));
}

// ---------------- Kernel 1: Riccati. Diagonal fast path + general MFMA path ----------
__global__ void __launch_bounds__(256, 1)
k1_riccati(const float* __restrict__ Fg, const float* __restrict__ Bg,
           const float* __restrict__ Hg, const float* __restrict__ LQg,
           const float* __restrict__ LRg, float* __restrict__ ws,
           float* __restrict__ covs) {
  __shared__ __align__(16) u16 smb[7 * 8192];
  __shared__ __align__(16) float Mf32[4096];
  __shared__ __align__(16) float Ppf32[4096];
  __shared__ __align__(16) float red[308];

  const int tid = threadIdx.x;
  const int l = tid & 63, w = tid >> 6, q = l >> 4, ln = l & 15;
  const int R = w >> 1, Cb = w & 1;

  // ---- diagonality detection ----
  {
    const int row = tid >> 2, cb = (tid & 3) << 4;
    float od = 0.f;
    const float* mats[5] = {Fg, Bg, Hg, LQg, LRg};
#pragma unroll
    for (int mi = 0; mi < 5; ++mi) {
      const float* M = mats[mi];
#pragma unroll
      for (int m = 0; m < 4; ++m) {
        f32x4v x = *(const f32x4v*)(M + row * 64 + cb + 4 * m);
        const int j0c = cb + 4 * m;
        if (j0c + 0 != row) od = fmaxf(od, fabsf(x.x));
        if (j0c + 1 != row) od = fmaxf(od, fabsf(x.y));
        if (j0c + 2 != row) od = fmaxf(od, fabsf(x.z));
        if (j0c + 3 != row) od = fmaxf(od, fabsf(x.w));
      }
    }
    const float odall = redmax(od, red, tid);
    if (odall == 0.f) {
      if (tid < 64) {
        const int e = tid;
        const float f = Fg[e * 65], b = Bg[e * 65], h = Hg[e * 65];
        const float lq = LQg[e * 65], lr = LRg[e * 65];
        const float qv = lq * lq, rv = lr * lr;
        float p = 1.f, kprev = 0.f, kcur = 0.f, om = 1.f;
        int tstar = SEQ - 1;
        for (int t = 0; t < SEQ; ++t) {
          const float pp = f * p * f + qv;
          const float s = h * pp * h + rv;
          const float k = pp * h / s;
          const float kh = k * h;
          const float omv = 1.f - kh;
          const float pn = omv * omv * pp + k * k * rv;
          float* Kt = ws + WS_K + (size_t)t * 4096 + e * 64;
          float* Ct = covs + (size_t)t * 4096 + e * 64;
          f32x4v z; z.x = 0.f; z.y = 0.f; z.z = 0.f; z.w = 0.f;
#pragma unroll
          for (int m = 0; m < 16; ++m) {
            *(f32x4v*)(Kt + 4 * m) = z;
            *(f32x4v*)(Ct + 4 * m) = z;
          }
          Kt[e] = k;
          Ct[e] = pn;
          float dk = (t == 0) ? 1e9f : fabsf(k - kprev);
#pragma unroll
          for (int off = 32; off > 0; off >>= 1) dk = fmaxf(dk, __shfl_xor(dk, off));
          p = pn; kprev = k; kcur = k; om = omv;
          if (dk < 1e-3f) { tstar = t; break; }
        }
        {
          const float astar = om * f, bpv = om * b;
          float* Ar = ws + WS_A + e * 64;
          float* Bp = ws + WS_BP + e * 64;
          float* Ks = ws + WS_KS + e * 64;
          f32x4v z; z.x = 0.f; z.y = 0.f; z.z = 0.f; z.w = 0.f;
#pragma unroll
          for (int m = 0; m < 16; ++m) {
            *(f32x4v*)(Ar + 4 * m) = z;
            *(f32x4v*)(Bp + 4 * m) = z;
            *(f32x4v*)(Ks + 4 * m) = z;
          }
          Ar[e] = astar; Bp[e] = bpv; Ks[e] = kcur;
          const float a2 = astar * astar, a4 = a2 * a2, a8 = a4 * a4;
          float a16 = fabsf(a8 * a8);
#pragma unroll
          for (int off = 32; off > 0; off >>= 1) a16 = fmaxf(a16, __shfl_xor(a16, off));
          if (e == 0) {
            ((int*)ws)[0] = tstar;
            ((int*)ws)[1] = (tstar <= 16 && a16 < 1e-5f) ? 1 : 0;
          }
        }
      }
      return;
    }
  }

  // ======== general path: split-bf16 MFMA Riccati ========
  u16* SF = smb;
  u16* SH = smb + 8192;
  u16* SX = smb + 2 * 8192;
  u16* S1 = smb + 3 * 8192;
  u16* S2 = smb + 4 * 8192;
  u16* S3 = smb + 5 * 8192;
  u16* S4 = smb + 6 * 8192;

  splitsrc(Fg, SF, nullptr, 0, 0, 0, tid);
  splitsrc(Hg, SH, nullptr, 0, 0, 0, tid);
  splitsrc(LQg, S1, nullptr, 0, 0, 0, tid);
  __syncthreads();
  Acc qacc = accZero(); mm(S1, S1, qacc, R, Cb, q, ln);
  __syncthreads();
  splitsrc(LRg, S1, nullptr, 0, 0, 0, tid);
  __syncthreads();
  Acc racc = accZero(); mm(S1, S1, racc, R, Cb, q, ln);
  __syncthreads();
  {
    const int row = tid >> 2, cb = (tid & 3) << 4;
    float v[16];
#pragma unroll
    for (int e = 0; e < 16; ++e) v[e] = ((cb + e) == row) ? 1.f : 0.f;
    emit16(v, row, cb, S4, nullptr);   // P0 = I
  }
  __syncthreads();

  int tstar = SEQ - 1;
  for (int t = 0; t < SEQ; ++t) {
    const u16* Wsrc = SF;
    if (t > 0) {
      Acc a = accZero(); mm(SF, S4, a, R, Cb, q, ln);
      storeC(Mf32, a, R, Cb, q, ln);
      __syncthreads();
      splitsrc(Mf32, S1, nullptr, 0, 0, 0, tid);
      __syncthreads();
      Wsrc = S1;
    }
    {
      Acc a = qacc; mm(Wsrc, SF, a, R, Cb, q, ln);
      storeC(Ppf32, a, R, Cb, q, ln);
      __syncthreads();
      splitsrc(Ppf32, S2, nullptr, 0, 0, 0, tid);
      __syncthreads();
    }
    {
      Acc a = accZero(); mm(SH, S2, a, R, Cb, q, ln);
      storeC(Mf32, a, R, Cb, q, ln);
      __syncthreads();
      splitsrc(Mf32, S3, S4, 0, 0, 0, tid);
      __syncthreads();
    }
    {
      Acc a = racc; mm(S3, SH, a, R, Cb, q, ln);
      storeC(Mf32, a, R, Cb, q, ln);
      __syncthreads();
      if (t == 0) {
        const int col = tid & 63, grp = tid >> 6;
        float s = 0.f;
        for (int r2 = grp * 16; r2 < grp * 16 + 16; ++r2) s += fabsf(Mf32[r2 * 64 + col]);
        red[tid] = s;
        __syncthreads();
        if (tid < 64) {
          float cs = red[tid] + red[64 + tid] + red[128 + tid] + red[192 + tid];
#pragma unroll
          for (int off = 32; off > 0; off >>= 1) cs = fmaxf(cs, __shfl_xor(cs, off));
          if (tid == 0) red[256] = 1.f / (cs * cs);
        }
        __syncthreads();
        const float sc = red[256];
        splitsrc(Mf32, SX, nullptr, 1, sc, 0, tid);
        __syncthreads();
      }
      splitsrc(Mf32, S2, nullptr, 0, 0, 0, tid);
      __syncthreads();
    }
    const int cap = (t == 0) ? 40 : 4;
    for (int it = 0; it < cap; ++it) {
      Acc e_ = accZero(); mm(S2, SX, e_, R, Cb, q, ln);
      float r = 0.f;
#pragma unroll
      for (int i = 0; i < 2; ++i)
#pragma unroll
        for (int j = 0; j < 2; ++j)
#pragma unroll
          for (int k = 0; k < 4; ++k) {
            const int gr = 32 * R + 16 * i + 4 * q + k;
            const int gc = 32 * Cb + 16 * j + ln;
            r = fmaxf(r, fabsf(e_.t[i][j][k] - ((gr == gc) ? 1.f : 0.f)));
          }
      const float rall = redmax(r, red, tid);
      if (rall < 5e-4f) break;
      storeC(Mf32, e_, R, Cb, q, ln);
      __syncthreads();
      splitsrc(Mf32, nullptr, S1, 2, 0, 2.0f, tid);
      __syncthreads();
      Acc x2 = accZero(); mm(SX, S1, x2, R, Cb, q, ln);
      storeC(Mf32, x2, R, Cb, q, ln);
      __syncthreads();
      splitsrc(Mf32, SX, nullptr, 0, 0, 0, tid);
      __syncthreads();
      if (rall * rall < 1e-4f) break;
    }
    __syncthreads();
    float dk;
    {
      Acc a = accZero(); mm(SX, S4, a, R, Cb, q, ln);
      storeC(Mf32, a, R, Cb, q, ln);
      __syncthreads();
      const int row = tid >> 2, cb = (tid & 3) << 4;
      float v[16]; float dmax = (t == 0) ? 1e9f : 0.f;
      float* wrow = ws + WS_K + (size_t)t * 4096 + row * 64 + cb;
#pragma unroll
      for (int m = 0; m < 4; ++m) {
        f32x4v x = *(const f32x4v*)(Mf32 + row * 64 + cb + 4 * m);
        v[4 * m] = x.x; v[4 * m + 1] = x.y; v[4 * m + 2] = x.z; v[4 * m + 3] = x.w;
        *(f32x4v*)(wrow + 4 * m) = x;
      }
      if (t > 0) {
        const float* prow = wrow - 4096;
#pragma unroll
        for (int m = 0; m < 4; ++m) {
          f32x4v p = *(const f32x4v*)(prow + 4 * m);
          dmax = fmaxf(dmax, fmaxf(fmaxf(fabsf(v[4 * m] - p.x), fabsf(v[4 * m + 1] - p.y)),
                                   fmaxf(fabsf(v[4 * m + 2] - p.z), fabsf(v[4 * m + 3] - p.w))));
        }
      }
      emit16(v, row, cb, nullptr, S1);
      dk = redmax(dmax, red, tid);
    }
    {
      Acc a = accZero(); mm(S1, S4, a, R, Cb, q, ln);
      storeC(Mf32, a, R, Cb, q, ln);
      __syncthreads();
      const int row = tid >> 2, cb = (tid & 3) << 4;
      float pv[16];
#pragma unroll
      for (int m = 0; m < 4; ++m) {
        f32x4v mij = *(const f32x4v*)(Mf32 + row * 64 + cb + 4 * m);
        f32x4v pp  = *(const f32x4v*)(Ppf32 + row * 64 + cb + 4 * m);
        pv[4 * m]     = pp.x - 0.5f * (mij.x + Mf32[(cb + 4 * m + 0) * 64 + row]);
        pv[4 * m + 1] = pp.y - 0.5f * (mij.y + Mf32[(cb + 4 * m + 1) * 64 + row]);
        pv[4 * m + 2] = pp.z - 0.5f * (mij.z + Mf32[(cb + 4 * m + 2) * 64 + row]);
        pv[4 * m + 3] = pp.w - 0.5f * (mij.w + Mf32[(cb + 4 * m + 3) * 64 + row]);
      }
      float* crow = covs + (size_t)t * 4096 + row * 64 + cb;
#pragma unroll
      for (int m = 0; m < 4; ++m) {
        f32x4v o; o.x = pv[4 * m]; o.y = pv[4 * m + 1]; o.z = pv[4 * m + 2]; o.w = pv[4 * m + 3];
        *(f32x4v*)(crow + 4 * m) = o;
      }
      emit16(pv, row, cb, S4, nullptr);
      __syncthreads();
    }
    if (dk < 1e-3f) { tstar = t; break; }
  }

  {
    Acc a = accZero(); mm(S1, SH, a, R, Cb, q, ln);
    storeC(Mf32, a, R, Cb, q, ln);
    __syncthreads();
    splitsrc(Mf32, S2, nullptr, 2, 0, 1.0f, tid);
    __syncthreads();
  }
  splitsrc(Fg, nullptr, S3, 0, 0, 0, tid);
  __syncthreads();
  {
    Acc a = accZero(); mm(S2, S3, a, R, Cb, q, ln);
    storeC(Mf32, a, R, Cb, q, ln);
#pragma unroll
    for (int i = 0; i < 2; ++i)
#pragma unroll
      for (int j = 0; j < 2; ++j)
#pragma unroll
        for (int k = 0; k < 4; ++k)
          ws[WS_A + (size_t)((32 * R + 16 * i + 4 * q + k) * 64 + 32 * Cb + 16 * j + ln)] = a.t[i][j][k];
    __syncthreads();
    splitsrc(Mf32, S1, S4, 0, 0, 0, tid);
    __syncthreads();
  }
  splitsrc(Bg, nullptr, S3, 0, 0, 0, tid);
  __syncthreads();
  {
    Acc a = accZero(); mm(S2, S3, a, R, Cb, q, ln);
#pragma unroll
    for (int i = 0; i < 2; ++i)
#pragma unroll
      for (int j = 0; j < 2; ++j)
#pragma unroll
        for (int k = 0; k < 4; ++k)
          ws[WS_BP + (size_t)((32 * R + 16 * i + 4 * q + k) * 64 + 32 * Cb + 16 * j + ln)] = a.t[i][j][k];
  }
  {
    const int row = tid >> 2, cb = (tid & 3) << 4;
    const float* srcr = ws + WS_K + (size_t)tstar * 4096 + row * 64 + cb;
    float* dstr = ws + WS_KS + row * 64 + cb;
#pragma unroll
    for (int m = 0; m < 4; ++m) *(f32x4v*)(dstr + 4 * m) = *(const f32x4v*)(srcr + 4 * m);
  }
  __syncthreads();
  {
    Acc a = accZero(); mm(S1, S4, a, R, Cb, q, ln);
    storeC(Mf32, a, R, Cb, q, ln); __syncthreads();
    splitsrc(Mf32, S2, S3, 0, 0, 0, tid); __syncthreads();
  }
  {
    Acc a = accZero(); mm(S2, S3, a, R, Cb, q, ln);
    storeC(Mf32, a, R, Cb, q, ln); __syncthreads();
    splitsrc(Mf32, S1, S4, 0, 0, 0, tid); __syncthreads();
  }
  {
    Acc a = accZero(); mm(S1, S4, a, R, Cb, q, ln);
    storeC(Mf32, a, R, Cb, q, ln); __syncthreads();
    splitsrc(Mf32, S2, S3, 0, 0, 0, tid); __syncthreads();
  }
  {
    Acc a = accZero(); mm(S2, S3, a, R, Cb, q, ln);
    float am = 0.f;
#pragma unroll
    for (int i = 0; i < 2; ++i)
#pragma unroll
      for (int j = 0; j < 2; ++j)
#pragma unroll
        for (int k = 0; k < 4; ++k) am = fmaxf(am, fabsf(a.t[i][j][k]));
    const float amax = redmax(am, red, tid);
    if (tid == 0) {
      ((int*)ws)[0] = tstar;
      ((int*)ws)[1] = (tstar <= 16 && amax < 1e-5f) ? 1 : 0;
    }
  }
}

// --- Kernel 2: x-rec WGs first; broadcast = 2048 fine-grained WGs w/ NT stores -------
#define NX2 1024   // 8 chunks x 128 batches  (blockIdx 0..1023)
#define NB2 2048   // 128 batches x 16 s-tiles of 16 rows = 256 KB/WG (blockIdx >= NX2)

__global__ void __launch_bounds__(256, 4)
k2_fused(const float* __restrict__ x0, const float* __restrict__ U,
         const float* __restrict__ Y, const float* __restrict__ Fg,
         const float* __restrict__ Bg, const float* __restrict__ Hg,
         const float* __restrict__ ws, float* __restrict__ preds,
         float* __restrict__ covs) {
  const int tid = threadIdx.x;
  const int wg = blockIdx.x;
  const int tstar = ((const int*)ws)[0];
  const int flag  = ((const int*)ws)[1];

  if (wg >= NX2) {
    // covs broadcast: WG (b, s-tile) writes 16 consecutive s-rows = 256 KB linear,
    // via nontemporal (no-allocate) stores to keep the 533 MB stream out of L2.
    const int bw = wg - NX2;
    const int b = bw >> 4, st = (bw & 15) << 4;
    const f32x4v* srcInf = (const f32x4v*)(covs + (size_t)tstar * 4096);
    f32x4v r0 = srcInf[tid], r1 = srcInf[256 + tid];
    f32x4v r2 = srcInf[512 + tid], r3 = srcInf[768 + tid];
    for (int s = st; s < st + 16; ++s) {
      f32x4v* dst = (f32x4v*)(covs + ((size_t)b * SEQ + s) * 4096);
      if (s <= tstar) {
        if (b == 0) continue;  // k1 wrote batch-0 rows 0..tstar
        const f32x4v* src = (const f32x4v*)(covs + (size_t)s * 4096);
        __builtin_nontemporal_store(src[tid],       dst + tid);
        __builtin_nontemporal_store(src[256 + tid], dst + 256 + tid);
        __builtin_nontemporal_store(src[512 + tid], dst + 512 + tid);
        __builtin_nontemporal_store(src[768 + tid], dst + 768 + tid);
      } else {
        __builtin_nontemporal_store(r0, dst + tid);
        __builtin_nontemporal_store(r1, dst + 256 + tid);
        __builtin_nontemporal_store(r2, dst + 512 + tid);
        __builtin_nontemporal_store(r3, dst + 768 + tid);
      }
    }
  } else {
    const int c = wg >> 7, b = wg & 127;
    const int e = tid >> 2, q = tid & 3;
    const int co = q << 4;  // column offset of this thread's quarter-row
    __shared__ __align__(16) float xa[64], xb[64], inn[64], us[2][64], ys[2][64];

    if (c == 0) {
      // exact path: time-varying K for t <= t*; covers all t if !flag
      const int t1 = flag ? 32 : SEQ;
      float4 Fr[4], Br[4], Hr[4], Kr[4];
      {
        const float4* fp = (const float4*)(Fg + e * 64 + co);
        const float4* bp = (const float4*)(Bg + e * 64 + co);
        const float4* hp = (const float4*)(Hg + e * 64 + co);
#pragma unroll
        for (int m = 0; m < 4; ++m) { Fr[m] = fp[m]; Br[m] = bp[m]; Hr[m] = hp[m]; }
      }
      if (tid < 64) xa[tid] = x0[b * 64 + tid];
      int staged = -1;
      for (int t = 0; t < t1; ++t) {
        const int se = (t < tstar) ? t : tstar;
        if (se != staged) {
          const float4* kp = (const float4*)(ws + WS_K + (size_t)se * 4096 + e * 64 + co);
#pragma unroll
          for (int m = 0; m < 4; ++m) Kr[m] = kp[m];
          staged = se;
        }
        if (tid < 64) us[0][tid] = U[((size_t)b * SEQ + t) * 64 + tid];
        else if (tid < 128) ys[0][tid - 64] = Y[((size_t)b * SEQ + t) * 64 + (tid - 64)];
        __syncthreads();
        const float4* xv4 = (const float4*)xa;
        const float4* us4 = (const float4*)us[0];
        float v = 0.f;
#pragma unroll
        for (int m = 0; m < 4; ++m) {
          v = dot4(Fr[m], xv4[q * 4 + m], v);
          v = dot4(Br[m], us4[q * 4 + m], v);
        }
        v += __shfl_xor(v, 1); v += __shfl_xor(v, 2);
        if (q == 0) xb[e] = v;
        __syncthreads();
        const float4* xp4 = (const float4*)xb;
        float wv = 0.f;
#pragma unroll
        for (int m = 0; m < 4; ++m) wv = dot4(Hr[m], xp4[q * 4 + m], wv);
        wv += __shfl_xor(wv, 1); wv += __shfl_xor(wv, 2);
        if (q == 0) inn[e] = ys[0][e] - wv;
        __syncthreads();
        const float4* in4 = (const float4*)inn;
        float z = 0.f;
#pragma unroll
        for (int m = 0; m < 4; ++m) z = dot4(Kr[m], in4[q * 4 + m], z);
        z += __shfl_xor(z, 1); z += __shfl_xor(z, 2);
        if (q == 0) xa[e] = xb[e] + z;
        __syncthreads();
        if (tid < 64) preds[((size_t)b * SEQ + t) * 64 + tid] = xa[tid];
      }
    } else {
      if (!flag) return;  // fallback: chunk 0 handles everything
      // steady chunk, ONE barrier/step: x_t = A* x + Bp u_t + K* y_t; burn-in 16
      const int tb = 32 * c - 16, out0 = 32 * c, t1 = 32 * c + 32;
      float4 Ar[4], Pr[4], Sr[4];
      {
        const float4* ap = (const float4*)(ws + WS_A + e * 64 + co);
        const float4* pp = (const float4*)(ws + WS_BP + e * 64 + co);
        const float4* sp = (const float4*)(ws + WS_KS + e * 64 + co);
#pragma unroll
        for (int m = 0; m < 4; ++m) { Ar[m] = ap[m]; Pr[m] = pp[m]; Sr[m] = sp[m]; }
      }
      float* xcur = xa;
      float* xnxt = xb;
      if (tid < 64) xcur[tid] = 0.f;
      float g = 0.f;
      if (tid < 64) g = U[((size_t)b * SEQ + tb) * 64 + tid];
      else if (tid < 128) g = Y[((size_t)b * SEQ + tb) * 64 + (tid - 64)];
      if (tid < 64) us[0][tid] = g;
      else if (tid < 128) ys[0][tid - 64] = g;
      if (tb + 1 < t1) {
        if (tid < 64) g = U[((size_t)b * SEQ + tb + 1) * 64 + tid];
        else if (tid < 128) g = Y[((size_t)b * SEQ + tb + 1) * 64 + (tid - 64)];
      }
      __syncthreads();
      int pb = 0;
      for (int t = tb; t < t1; ++t) {
        const float4* xv4 = (const float4*)xcur;
        const float4* us4 = (const float4*)us[pb];
        const float4* ys4 = (const float4*)ys[pb];
        float v = 0.f;
#pragma unroll
        for (int m = 0; m < 4; ++m) {
          v = dot4(Ar[m], xv4[q * 4 + m], v);
          v = dot4(Pr[m], us4[q * 4 + m], v);
          v = dot4(Sr[m], ys4[q * 4 + m], v);
        }
        v += __shfl_xor(v, 1); v += __shfl_xor(v, 2);
        if (q == 0) xnxt[e] = v;
        if (t >= out0 && q == 0) preds[((size_t)b * SEQ + t) * 64 + e] = v;
        if (t + 1 < t1) {  // stage next inputs into the other buffer; prefetch t+2
          if (tid < 64) us[pb ^ 1][tid] = g;
          else if (tid < 128) ys[pb ^ 1][tid - 64] = g;
          if (t + 2 < t1) {
            if (tid < 64) g = U[((size_t)b * SEQ + t + 2) * 64 + tid];
            else if (tid < 128) g = Y[((size_t)b * SEQ + t + 2) * 64 + (tid - 64)];
          }
        }
        __syncthreads();  // xnxt visible; us/ys[pb^1] staged; us/ys[pb] free
        { float* tp = xcur; xcur = xnxt; xnxt = tp; }
        pb ^= 1;
      }
    }
  }
}

extern "C" void kernel_launch(void* const* d_in, const int* in_sizes, int n_in,
                              void* d_out, int out_size, void* d_ws, size_t ws_size,
                              hipStream_t stream) {
  (void)in_sizes; (void)n_in; (void)out_size; (void)ws_size;
  const float* x0 = (const float*)d_in[0];
  const float* U  = (const float*)d_in[1];
  const float* Y  = (const float*)d_in[2];
  const float* F  = (const float*)d_in[3];
  const float* B  = (const float*)d_in[4];
  const float* H  = (const float*)d_in[5];
  const float* LQ = (const float*)d_in[6];
  const float* LR = (const float*)d_in[7];
  float* preds = (float*)d_out;
  float* covs  = preds + (size_t)BATCH * SEQ * 64;
  float* ws    = (float*)d_ws;  // needs ~4.25 MB

  hipLaunchKernelGGL(k1_riccati, dim3(1), dim3(256), 0, stream,
                     F, B, H, LQ, LR, ws, covs);
  hipLaunchKernelGGL(k2_fused, dim3(NX2 + NB2), dim3(256), 0, stream,
                     x0, U, Y, F, B, H, ws, preds, covs);
}